// Round 7
// baseline (329.526 us; speedup 1.0000x reference)
//
#include <hip/hip_runtime.h>

// SectorAttentionV2 on MI355X (gfx950) — round 7
//   GEMM rewritten: 2-phase double-buffered pipeline, all staging via
//   global_load_lds (A staged as raw f32, cvt-on-read), XOR-swizzled LDS.
//   Three identical GEMM dispatches (Q, K, V). attn unchanged.

typedef unsigned short u16;
typedef unsigned int u32;
typedef __attribute__((ext_vector_type(8))) short bf16x8;
typedef __attribute__((ext_vector_type(4))) float f32x4;
typedef __attribute__((ext_vector_type(8))) unsigned short u16x8;
typedef __attribute__((ext_vector_type(4))) unsigned int u32x4;

__device__ __forceinline__ u16 f2b(float f) {
  u32 u = __float_as_uint(f);
  return (u16)((u + 0x7FFFu + ((u >> 16) & 1u)) >> 16);  // RNE
}
__device__ __forceinline__ float b2f(u16 v) { return __uint_as_float(((u32)v) << 16); }
__device__ __forceinline__ float b2f_lo(u32 d) { return __uint_as_float(d << 16); }
__device__ __forceinline__ float b2f_hi(u32 d) { return __uint_as_float(d & 0xffff0000u); }
__device__ __forceinline__ u32 cvt_pk(float lo, float hi) {
  u32 r;
  asm("v_cvt_pk_bf16_f32 %0, %1, %2" : "=v"(r) : "v"(lo), "v"(hi));
  return r;
}
#define GLDS(g, l)                                                                     \
  __builtin_amdgcn_global_load_lds((const __attribute__((address_space(1))) void*)(g), \
                                   (__attribute__((address_space(3))) void*)(l), 16, 0, 0)

// ---------------- weight transpose + cvt ----------------
__global__ __launch_bounds__(256) void wt_kernel(const float* __restrict__ Wq,
                                                 const float* __restrict__ Wk,
                                                 const float* __restrict__ Wv,
                                                 u16* __restrict__ Wt) {
  const float* W = (blockIdx.y == 0) ? Wq : (blockIdx.y == 1) ? Wk : Wv;
  int g = blockIdx.x * 256 + threadIdx.x;
  int n = g >> 9, k = g & 511;
  Wt[(size_t)blockIdx.y * 262144 + g] = f2b(W[k * 512 + n]);
}

// ---------------- bias MLP ----------------
// biasw[((b*8+nh)*4+p)*4+ks][w8192] f32
__global__ __launch_bounds__(256) void bias_kernel(
    const float* __restrict__ xpos, const float* __restrict__ spos,
    const float* __restrict__ pw1, const float* __restrict__ pb1,
    const float* __restrict__ bng, const float* __restrict__ bnb,
    const float* __restrict__ bnm, const float* __restrict__ bnv,
    const float* __restrict__ pw2, const float* __restrict__ pb2,
    float* __restrict__ biasw) {
  int t = threadIdx.x;
  int wl = t & 63, p = t >> 6;
  int n = blockIdx.x * 64 + wl;
  int b = n >> 13, w = n & 8191;

  float Am[16], Bm[16], Cm[16];
#pragma unroll
  for (int m = 0; m < 16; ++m) {
    float scv = bng[m] * rsqrtf(bnv[m] + 1e-5f);
    Am[m] = pw1[2 * m] * scv;
    Bm[m] = pw1[2 * m + 1] * scv;
    Cm[m] = (pb1[m] - bnm[m]) * scv + bnb[m];
  }
  size_t xi = ((size_t)(b * 32768 + p * 8192 + w)) * 2;
  float xp0 = xpos[xi], xp1 = xpos[xi + 1];
#pragma unroll
  for (int ks = 0; ks < 4; ++ks) {
    size_t si = ((size_t)((b * 4 + ks) * 8192 + w)) * 2;
    float r0 = xp0 - spos[si];
    float r1 = xp1 - spos[si + 1];
    float o[8];
#pragma unroll
    for (int oo = 0; oo < 8; ++oo) o[oo] = pb2[oo];
#pragma unroll
    for (int m = 0; m < 16; ++m) {
      float h = fmaxf(Am[m] * r0 + Bm[m] * r1 + Cm[m], 0.f);
#pragma unroll
      for (int oo = 0; oo < 8; ++oo) o[oo] += pw2[oo * 16 + m] * h;
    }
#pragma unroll
    for (int oo = 0; oo < 8; ++oo)
      biasw[((size_t)(((b * 8 + oo) * 4 + p) * 4 + ks)) * 8192 + w] = o[oo];
  }
}

// ---------------- GEMM: Out[m][c] = A(f32)[65536x512] @ Bt(bf16 [n][k]) + bias ----------------
// BM=128, BN=128, BK=32, double-buffered, all staging via global_load_lds.
// A staged raw f32 (LDS [128][32] f32, granule-XOR-swizzled), cvt on read.
__global__ __launch_bounds__(256, 3) void gemm_kernel(const float* __restrict__ A,
                                                      const u16* __restrict__ Bt,
                                                      const float* __restrict__ biasv,
                                                      u16* __restrict__ Out) {
  __shared__ u16 lds[24576];  // A dbuf 2x8192 u16 (f32 tile), B dbuf 2x4096 u16
  const int t = threadIdx.x, lane = t & 63, wv = t >> 6;
  const int id = (int)blockIdx.x;
  const int lg = (id & 7) * 256 + (id >> 3);  // XCD bijective swizzle (2048 % 8 == 0)
  const int mt = (lg >> 2) * 128, nt = (lg & 3) * 128;  // n fastest: A-panel L2 reuse
  const int fr = lane & 15, kg = lane >> 4;
  const int wm = (wv & 1) * 64, wn = (wv >> 1) * 64;

  // staging source swizzles (rule 21: linear LDS dest + inverse-swizzled source)
  const int arow = lane >> 3;                 // 0..7 (row within A inst-group)
  const int agr = (lane & 7) ^ arow;          // A source f32-granule (4 f32 each)
  const int brow = lane >> 2;                 // 0..15 (row within B inst-group)
  const int bgr = (lane & 3) ^ (brow & 3);    // B source granule (8 bf16 each)

  const float* Abase = A + (size_t)mt * 512;
  const u16* Bbase = Bt + (size_t)nt * 512;

  f32x4 acc[4][4];
#pragma unroll
  for (int i = 0; i < 4; ++i)
#pragma unroll
    for (int j = 0; j < 4; ++j) acc[i][j] = (f32x4){0.f, 0.f, 0.f, 0.f};

#define STAGE(buf, kt)                                                              \
  {                                                                                 \
    u16* Ab_ = lds + (buf)*8192;                                                    \
    u16* Bb_ = lds + 16384 + (buf)*4096;                                            \
    _Pragma("unroll") for (int ii = 0; ii < 4; ++ii) {                              \
      int inst = wv * 4 + ii;                                                       \
      GLDS(Abase + (size_t)(inst * 8 + arow) * 512 + (kt) + agr * 4,                \
           Ab_ + inst * 512);                                                       \
    }                                                                               \
    _Pragma("unroll") for (int ii = 0; ii < 2; ++ii) {                              \
      int inst = wv * 2 + ii;                                                       \
      GLDS(Bbase + (size_t)(inst * 16 + brow) * 512 + (kt) + bgr * 8,               \
           Bb_ + inst * 512);                                                       \
    }                                                                               \
  }

  STAGE(0, 0);
  __syncthreads();

  for (int ki = 0; ki < 16; ++ki) {
    int cur = ki & 1;
    if (ki < 15) STAGE(cur ^ 1, (ki + 1) * 32);
    const u16* Ab = lds + cur * 8192;
    const u16* Bb = lds + 16384 + cur * 4096;
    bf16x8 af[4], bfr[4];
#pragma unroll
    for (int i = 0; i < 4; ++i) {
      int r = wm + i * 16 + fr;
      int p0 = (2 * kg) ^ (r & 7), p1 = (2 * kg + 1) ^ (r & 7);
      f32x4 a0 = *(const f32x4*)&Ab[r * 64 + p0 * 8];
      f32x4 a1 = *(const f32x4*)&Ab[r * 64 + p1 * 8];
      union { bf16x8 v; u32 w[4]; } u;
      u.w[0] = cvt_pk(a0[0], a0[1]);
      u.w[1] = cvt_pk(a0[2], a0[3]);
      u.w[2] = cvt_pk(a1[0], a1[1]);
      u.w[3] = cvt_pk(a1[2], a1[3]);
      af[i] = u.v;
    }
#pragma unroll
    for (int j = 0; j < 4; ++j) {
      int r = wn + j * 16 + fr;
      int pos = kg ^ (r & 3);
      bfr[j] = *(const bf16x8*)&Bb[r * 32 + pos * 8];
    }
#pragma unroll
    for (int i = 0; i < 4; ++i)
#pragma unroll
      for (int j = 0; j < 4; ++j)
        acc[i][j] = __builtin_amdgcn_mfma_f32_16x16x32_bf16(af[i], bfr[j], acc[i][j], 0, 0, 0);
    __syncthreads();  // drains GLDS (buf^1 ready) + frees buf for next STAGE
  }
#undef STAGE

  // epilogue: stage to LDS (pad 136), flush row-major coalesced (1KB/instr)
  u16* Clds = lds;  // 128*136 = 17408 u16 <= 24576
#pragma unroll
  for (int i = 0; i < 4; ++i)
#pragma unroll
    for (int r = 0; r < 4; ++r) {
      int row = wm + i * 16 + kg * 4 + r;
#pragma unroll
      for (int j = 0; j < 4; ++j) {
        int ch = wn + j * 16 + fr;
        Clds[row * 136 + ch] = f2b(acc[i][j][r] + biasv[nt + ch]);
      }
    }
  __syncthreads();
#pragma unroll
  for (int c = 0; c < 8; ++c) {
    int off = c * 2048 + t * 8;
    int row = off >> 7, col = off & 127;
    *(u16x8*)(Out + (size_t)(mt + row) * 512 + nt + col) = *(const u16x8*)&Clds[row * 136 + col];
  }
}

// ---------------- attention ----------------
// block = (b,u,cg8,nh8); lane = col; wave wv owns d in [wv*16, wv*16+16)
// K/V tiles staged in LDS via global_load_lds; rows r=d*4+ks, 64 cols.
__global__ __launch_bounds__(256, 2) void attn_kernel(const u16* __restrict__ Qt,
                                                      const u16* __restrict__ Kt,
                                                      const u16* __restrict__ Vt,
                                                      const float* __restrict__ biasw,
                                                      float* __restrict__ out) {
  __shared__ u16 kvlds[32768];  // K [256][64] then V [256][64]
  __shared__ float X[4096];     // partial-score exchange [64][64]
  const int t = threadIdx.x, lane = t & 63, wv = t >> 6;
  const int blk = blockIdx.x;
  const int nh = blk & 7, cg = (blk >> 3) & 7, u = (blk >> 6) & 15, b = blk >> 10;
  const int col = cg * 64 + lane;
  const int chb = nh * 64 + wv * 16;

  // stage this wave's K/V rows (d in [wv*16,wv*16+16), all 4 ks): 8+8 async instrs
  {
    const size_t gb = (size_t)(b * 32768 + nh * 4096 + u) * 512 + cg * 64 + (lane & 7) * 8;
#pragma unroll
    for (int ii = 0; ii < 8; ++ii) {
      int i = wv * 8 + ii;
      int r = i * 8 + (lane >> 3);          // LDS row = d*4+ks
      int d = r >> 2, ks = r & 3;
      size_t go = gb + (size_t)(d * 64 + ks * 16) * 512;
      GLDS(Kt + go, &kvlds[i * 512]);
      GLDS(Vt + go, &kvlds[16384 + i * 512]);
    }
  }

  // Q into regs: 2x16B per p
  u32x4 q0[4], q1[4];
#pragma unroll
  for (int p = 0; p < 4; ++p) {
    const u16* qp = Qt + (size_t)(b * 32768 + p * 8192 + u * 512 + col) * 512 + chb;
    q0[p] = *(const u32x4*)qp;
    q1[p] = *(const u32x4*)(qp + 8);
  }
  // bias into regs
  float br[16];
  const size_t bbase = ((size_t)(b * 8 + nh) * 16) * 8192 + u * 512 + col;
#pragma unroll
  for (int pk = 0; pk < 16; ++pk) br[pk] = biasw[bbase + (size_t)pk * 8192];

  asm volatile("s_waitcnt vmcnt(0)" ::: "memory");
  __builtin_amdgcn_sched_barrier(0);

  // QK^T from K-LDS (this wave's 16 d's)
  float sc[4][4];
#pragma unroll
  for (int p = 0; p < 4; ++p)
#pragma unroll
    for (int k = 0; k < 4; ++k) sc[p][k] = 0.f;
#pragma unroll
  for (int dd = 0; dd < 16; ++dd) {
    int rb = (wv * 16 + dd) * 4;
    float kv[4];
#pragma unroll
    for (int ks = 0; ks < 4; ++ks) kv[ks] = b2f(kvlds[(rb + ks) * 64 + lane]);
    float qd[4];
#pragma unroll
    for (int p = 0; p < 4; ++p) {
      u32 word = (dd < 8) ? q0[p][(dd >> 1) & 3] : q1[p][(dd >> 1) & 3];
      qd[p] = (dd & 1) ? b2f_hi(word) : b2f_lo(word);
    }
#pragma unroll
    for (int p = 0; p < 4; ++p)
#pragma unroll
      for (int ks = 0; ks < 4; ++ks) sc[p][ks] += qd[p] * kv[ks];
  }

  // exchange partial d-slices
#pragma unroll
  for (int pk = 0; pk < 16; ++pk) X[(wv * 16 + pk) * 64 + lane] = sc[pk >> 2][pk & 3];
  __syncthreads();

  float a[4][4];
#pragma unroll
  for (int p = 0; p < 4; ++p) {
    float s[4];
#pragma unroll
    for (int ks = 0; ks < 4; ++ks) {
      int pk = p * 4 + ks;
      float tot = X[pk * 64 + lane] + X[(16 + pk) * 64 + lane] + X[(32 + pk) * 64 + lane] +
                  X[(48 + pk) * 64 + lane];
      s[ks] = tot * 0.125f + br[pk];
    }
    float mx = fmaxf(fmaxf(s[0], s[1]), fmaxf(s[2], s[3]));
    float e0 = __expf(s[0] - mx), e1 = __expf(s[1] - mx), e2 = __expf(s[2] - mx),
          e3 = __expf(s[3] - mx);
    float inv = 1.f / (e0 + e1 + e2 + e3);
    a[p][0] = e0 * inv; a[p][1] = e1 * inv; a[p][2] = e2 * inv; a[p][3] = e3 * inv;
  }

  // PV from V-LDS
  float o[4][16];
#pragma unroll
  for (int dd = 0; dd < 16; ++dd) {
    int rb = (wv * 16 + dd) * 4;
    float vv[4];
#pragma unroll
    for (int ks = 0; ks < 4; ++ks) vv[ks] = b2f(kvlds[16384 + (rb + ks) * 64 + lane]);
#pragma unroll
    for (int p = 0; p < 4; ++p)
      o[p][dd] = a[p][0] * vv[0] + a[p][1] * vv[1] + a[p][2] * vv[2] + a[p][3] * vv[3];
  }
#pragma unroll
  for (int p = 0; p < 4; ++p) {
    float* op = out + (size_t)(b * 32768 + p * 8192 + u * 512 + col) * 512 + chb;
#pragma unroll
    for (int c4 = 0; c4 < 4; ++c4) {
      float4 vv = {o[p][c4 * 4 + 0], o[p][c4 * 4 + 1], o[p][c4 * 4 + 2], o[p][c4 * 4 + 3]};
      *(float4*)(op + c4 * 4) = vv;
    }
  }
}

// ---------------- launch ----------------
extern "C" void kernel_launch(void* const* d_in, const int* in_sizes, int n_in,
                              void* d_out, int out_size, void* d_ws, size_t ws_size,
                              hipStream_t stream) {
  (void)in_sizes; (void)n_in; (void)out_size; (void)ws_size;
  const float* s     = (const float*)d_in[0];
  const float* x     = (const float*)d_in[1];
  const float* s_pos = (const float*)d_in[2];
  const float* x_pos = (const float*)d_in[3];
  const float* Wq = (const float*)d_in[4];  const float* bq = (const float*)d_in[5];
  const float* Wk = (const float*)d_in[6];  const float* bk = (const float*)d_in[7];
  const float* Wv = (const float*)d_in[8];  const float* bv = (const float*)d_in[9];
  const float* pw1 = (const float*)d_in[10]; const float* pb1 = (const float*)d_in[11];
  const float* bng = (const float*)d_in[12]; const float* bnb = (const float*)d_in[13];
  const float* bnm = (const float*)d_in[14]; const float* bnv = (const float*)d_in[15];
  const float* pw2 = (const float*)d_in[16]; const float* pb2 = (const float*)d_in[17];
  float* out = (float*)d_out;

  char* ws = (char*)d_ws;
  u16* Qt = (u16*)ws;                        // 67,108,864 B
  u16* Kt = (u16*)(ws + 67108864);           // 67,108,864 B
  u16* Vt = (u16*)(ws + 134217728);          // 67,108,864 B
  float* biasw = (float*)(ws + 201326592);   //  8,388,608 B
  u16* Wt = (u16*)(ws + 209715200);          //  1,572,864 B

  wt_kernel<<<dim3(1024, 3), 256, 0, stream>>>(Wq, Wk, Wv, Wt);
  bias_kernel<<<dim3(256), 256, 0, stream>>>(x_pos, s_pos, pw1, pb1, bng, bnb, bnm, bnv,
                                             pw2, pb2, biasw);
  gemm_kernel<<<dim3(2048), 256, 0, stream>>>(x, Wt, bq, Qt);
  gemm_kernel<<<dim3(2048), 256, 0, stream>>>(s, Wt + 262144, bk, Kt);
  gemm_kernel<<<dim3(2048), 256, 0, stream>>>(s, Wt + 524288, bv, Vt);
  attn_kernel<<<dim3(2048), 256, 0, stream>>>(Qt, Kt, Vt, biasw, out);
}

// Round 8
// 292.427 us; speedup vs baseline: 1.1269x; 1.1269x over previous
//
#include <hip/hip_runtime.h>

// SectorAttentionV2 on MI355X (gfx950) — round 8
//   GEMMs: 2-phase double-buffer with counted vmcnt + RAW s_barrier (prefetch
//   survives the barrier). K+V fused (single s read). attn unchanged.

typedef unsigned short u16;
typedef unsigned int u32;
typedef __attribute__((ext_vector_type(8))) short bf16x8;
typedef __attribute__((ext_vector_type(4))) float f32x4;
typedef __attribute__((ext_vector_type(8))) unsigned short u16x8;
typedef __attribute__((ext_vector_type(4))) unsigned int u32x4;

__device__ __forceinline__ u16 f2b(float f) {
  u32 u = __float_as_uint(f);
  return (u16)((u + 0x7FFFu + ((u >> 16) & 1u)) >> 16);  // RNE
}
__device__ __forceinline__ float b2f(u16 v) { return __uint_as_float(((u32)v) << 16); }
__device__ __forceinline__ float b2f_lo(u32 d) { return __uint_as_float(d << 16); }
__device__ __forceinline__ float b2f_hi(u32 d) { return __uint_as_float(d & 0xffff0000u); }
__device__ __forceinline__ u32 cvt_pk(float lo, float hi) {
  u32 r;
  asm("v_cvt_pk_bf16_f32 %0, %1, %2" : "=v"(r) : "v"(lo), "v"(hi));
  return r;
}
#define GLDS(g, l)                                                                     \
  __builtin_amdgcn_global_load_lds((const __attribute__((address_space(1))) void*)(g), \
                                   (__attribute__((address_space(3))) void*)(l), 16, 0, 0)

// ---------------- weight transpose + cvt ----------------
__global__ __launch_bounds__(256) void wt_kernel(const float* __restrict__ Wq,
                                                 const float* __restrict__ Wk,
                                                 const float* __restrict__ Wv,
                                                 u16* __restrict__ Wt) {
  const float* W = (blockIdx.y == 0) ? Wq : (blockIdx.y == 1) ? Wk : Wv;
  int g = blockIdx.x * 256 + threadIdx.x;
  int n = g >> 9, k = g & 511;
  Wt[(size_t)blockIdx.y * 262144 + g] = f2b(W[k * 512 + n]);
}

// ---------------- bias MLP ----------------
// biasw[((b*8+nh)*4+p)*4+ks][w8192] f32
__global__ __launch_bounds__(256) void bias_kernel(
    const float* __restrict__ xpos, const float* __restrict__ spos,
    const float* __restrict__ pw1, const float* __restrict__ pb1,
    const float* __restrict__ bng, const float* __restrict__ bnb,
    const float* __restrict__ bnm, const float* __restrict__ bnv,
    const float* __restrict__ pw2, const float* __restrict__ pb2,
    float* __restrict__ biasw) {
  int t = threadIdx.x;
  int wl = t & 63, p = t >> 6;
  int n = blockIdx.x * 64 + wl;
  int b = n >> 13, w = n & 8191;

  float Am[16], Bm[16], Cm[16];
#pragma unroll
  for (int m = 0; m < 16; ++m) {
    float scv = bng[m] * rsqrtf(bnv[m] + 1e-5f);
    Am[m] = pw1[2 * m] * scv;
    Bm[m] = pw1[2 * m + 1] * scv;
    Cm[m] = (pb1[m] - bnm[m]) * scv + bnb[m];
  }
  size_t xi = ((size_t)(b * 32768 + p * 8192 + w)) * 2;
  float xp0 = xpos[xi], xp1 = xpos[xi + 1];
#pragma unroll
  for (int ks = 0; ks < 4; ++ks) {
    size_t si = ((size_t)((b * 4 + ks) * 8192 + w)) * 2;
    float r0 = xp0 - spos[si];
    float r1 = xp1 - spos[si + 1];
    float o[8];
#pragma unroll
    for (int oo = 0; oo < 8; ++oo) o[oo] = pb2[oo];
#pragma unroll
    for (int m = 0; m < 16; ++m) {
      float h = fmaxf(Am[m] * r0 + Bm[m] * r1 + Cm[m], 0.f);
#pragma unroll
      for (int oo = 0; oo < 8; ++oo) o[oo] += pw2[oo * 16 + m] * h;
    }
#pragma unroll
    for (int oo = 0; oo < 8; ++oo)
      biasw[((size_t)(((b * 8 + oo) * 4 + p) * 4 + ks)) * 8192 + w] = o[oo];
  }
}

// ---------------- Q GEMM: BM=128 BN=128 BK=32, dbuf + counted vmcnt ----------------
__global__ __launch_bounds__(256, 3) void gemm_kernel(const float* __restrict__ A,
                                                      const u16* __restrict__ Bt,
                                                      const float* __restrict__ biasv,
                                                      u16* __restrict__ Out) {
  __shared__ u16 lds[24576];  // A dbuf 2x8192 u16 (f32 tile), B dbuf 2x4096 u16
  const int t = threadIdx.x, lane = t & 63, wv = t >> 6;
  const int id = (int)blockIdx.x;
  const int lg = (id & 7) * 256 + (id >> 3);  // XCD bijective swizzle (2048 % 8 == 0)
  const int mt = (lg >> 2) * 128, nt = (lg & 3) * 128;  // n fastest: A-panel L2 reuse
  const int fr = lane & 15, kg = lane >> 4;
  const int wm = (wv & 1) * 64, wn = (wv >> 1) * 64;

  // staging source swizzles (rule 21: linear LDS dest + inverse-swizzled source)
  const int arow = lane >> 3;                              // 0..7
  const int agr = (lane & 7) ^ arow;                       // A f32-granule (16B)
  const int brow = lane >> 2;                              // 0..15
  const int bgr = (lane & 3) ^ (brow & 3) ^ ((brow >> 2) & 3);  // B granule (16B)

  const float* Abase = A + (size_t)mt * 512;
  const u16* Bbase = Bt + (size_t)nt * 512;

  f32x4 acc[4][4];
#pragma unroll
  for (int i = 0; i < 4; ++i)
#pragma unroll
    for (int j = 0; j < 4; ++j) acc[i][j] = (f32x4){0.f, 0.f, 0.f, 0.f};

#define STAGEQ(buf, kt)                                                       \
  {                                                                           \
    u16* Ab_ = lds + (buf)*8192;                                              \
    u16* Bb_ = lds + 16384 + (buf)*4096;                                      \
    _Pragma("unroll") for (int ii = 0; ii < 4; ++ii) {                        \
      int inst = wv * 4 + ii;                                                 \
      GLDS(Abase + (size_t)(inst * 8 + arow) * 512 + (kt) + agr * 4,          \
           Ab_ + inst * 512);                                                 \
    }                                                                         \
    _Pragma("unroll") for (int ii = 0; ii < 2; ++ii) {                        \
      int inst = wv * 2 + ii;                                                 \
      GLDS(Bbase + (size_t)(inst * 16 + brow) * 512 + (kt) + bgr * 8,         \
           Bb_ + inst * 512);                                                 \
    }                                                                         \
  }

  STAGEQ(0, 0);

  for (int ki = 0; ki < 16; ++ki) {
    int cur = ki & 1;
    if (ki < 15) {
      STAGEQ(cur ^ 1, (ki + 1) * 32);
      asm volatile("s_waitcnt vmcnt(6)" ::: "memory");
    } else {
      asm volatile("s_waitcnt vmcnt(0)" ::: "memory");
    }
    __builtin_amdgcn_sched_barrier(0);
    __builtin_amdgcn_s_barrier();
    __builtin_amdgcn_sched_barrier(0);

    const u16* Ab = lds + cur * 8192;
    const u16* Bb = lds + 16384 + cur * 4096;
    bf16x8 af[4], bfr[4];
#pragma unroll
    for (int i = 0; i < 4; ++i) {
      int r = wm + i * 16 + fr;
      int p0 = (2 * kg) ^ (r & 7), p1 = (2 * kg + 1) ^ (r & 7);
      f32x4 a0 = *(const f32x4*)&Ab[r * 64 + p0 * 8];
      f32x4 a1 = *(const f32x4*)&Ab[r * 64 + p1 * 8];
      union { bf16x8 v; u32 w[4]; } u;
      u.w[0] = cvt_pk(a0[0], a0[1]);
      u.w[1] = cvt_pk(a0[2], a0[3]);
      u.w[2] = cvt_pk(a1[0], a1[1]);
      u.w[3] = cvt_pk(a1[2], a1[3]);
      af[i] = u.v;
    }
#pragma unroll
    for (int j = 0; j < 4; ++j) {
      int r = wn + j * 16 + fr;
      int pos = kg ^ (r & 3) ^ ((r >> 2) & 3);
      bfr[j] = *(const bf16x8*)&Bb[r * 32 + pos * 8];
    }
#pragma unroll
    for (int i = 0; i < 4; ++i)
#pragma unroll
      for (int j = 0; j < 4; ++j)
        acc[i][j] = __builtin_amdgcn_mfma_f32_16x16x32_bf16(af[i], bfr[j], acc[i][j], 0, 0, 0);

    __builtin_amdgcn_sched_barrier(0);
    __builtin_amdgcn_s_barrier();
    __builtin_amdgcn_sched_barrier(0);
  }
#undef STAGEQ

  // epilogue: stage to LDS (pad 136), flush row-major coalesced (1KB/instr)
  u16* Clds = lds;  // 128*136 = 17408 u16 <= 24576
#pragma unroll
  for (int i = 0; i < 4; ++i)
#pragma unroll
    for (int r = 0; r < 4; ++r) {
      int row = wm + i * 16 + kg * 4 + r;
#pragma unroll
      for (int j = 0; j < 4; ++j) {
        int ch = wn + j * 16 + fr;
        Clds[row * 136 + ch] = f2b(acc[i][j][r] + biasv[nt + ch]);
      }
    }
  __syncthreads();
#pragma unroll
  for (int c = 0; c < 8; ++c) {
    int off = c * 2048 + t * 8;
    int row = off >> 7, col = off & 127;
    *(u16x8*)(Out + (size_t)(mt + row) * 512 + nt + col) = *(const u16x8*)&Clds[row * 136 + col];
  }
}

// ---------------- fused K+V GEMM: shared A tile (dbuf), counted vmcnt ----------------
__global__ __launch_bounds__(256, 2) void gemmkv_kernel(const float* __restrict__ A,
                                                        const u16* __restrict__ BtK,
                                                        const u16* __restrict__ BtV,
                                                        const float* __restrict__ bK,
                                                        const float* __restrict__ bV,
                                                        u16* __restrict__ OutK,
                                                        u16* __restrict__ OutV) {
  __shared__ u16 lds[32768];  // A dbuf 2x8192, BK dbuf 2x4096, BV dbuf 2x4096
  const int t = threadIdx.x, lane = t & 63, wv = t >> 6;
  const int id = (int)blockIdx.x;
  const int lg = (id & 7) * 256 + (id >> 3);
  const int mt = (lg >> 2) * 128, nt = (lg & 3) * 128;
  const int fr = lane & 15, kg = lane >> 4;
  const int wm = (wv & 1) * 64, wn = (wv >> 1) * 64;

  const int arow = lane >> 3;
  const int agr = (lane & 7) ^ arow;
  const int brow = lane >> 2;
  const int bgr = (lane & 3) ^ (brow & 3) ^ ((brow >> 2) & 3);

  const float* Abase = A + (size_t)mt * 512;
  const u16* BbaseK = BtK + (size_t)nt * 512;
  const u16* BbaseV = BtV + (size_t)nt * 512;

  f32x4 accK[4][4], accV[4][4];
#pragma unroll
  for (int i = 0; i < 4; ++i)
#pragma unroll
    for (int j = 0; j < 4; ++j) {
      accK[i][j] = (f32x4){0.f, 0.f, 0.f, 0.f};
      accV[i][j] = (f32x4){0.f, 0.f, 0.f, 0.f};
    }

#define STAGEKV(buf, kt)                                                      \
  {                                                                           \
    u16* Ab_ = lds + (buf)*8192;                                              \
    u16* Bk_ = lds + 16384 + (buf)*4096;                                      \
    u16* Bv_ = lds + 24576 + (buf)*4096;                                      \
    _Pragma("unroll") for (int ii = 0; ii < 4; ++ii) {                        \
      int inst = wv * 4 + ii;                                                 \
      GLDS(Abase + (size_t)(inst * 8 + arow) * 512 + (kt) + agr * 4,          \
           Ab_ + inst * 512);                                                 \
    }                                                                         \
    _Pragma("unroll") for (int ii = 0; ii < 2; ++ii) {                        \
      int inst = wv * 2 + ii;                                                 \
      GLDS(BbaseK + (size_t)(inst * 16 + brow) * 512 + (kt) + bgr * 8,        \
           Bk_ + inst * 512);                                                 \
      GLDS(BbaseV + (size_t)(inst * 16 + brow) * 512 + (kt) + bgr * 8,        \
           Bv_ + inst * 512);                                                 \
    }                                                                         \
  }

  STAGEKV(0, 0);

  for (int ki = 0; ki < 16; ++ki) {
    int cur = ki & 1;
    if (ki < 15) {
      STAGEKV(cur ^ 1, (ki + 1) * 32);
      asm volatile("s_waitcnt vmcnt(8)" ::: "memory");
    } else {
      asm volatile("s_waitcnt vmcnt(0)" ::: "memory");
    }
    __builtin_amdgcn_sched_barrier(0);
    __builtin_amdgcn_s_barrier();
    __builtin_amdgcn_sched_barrier(0);

    const u16* Ab = lds + cur * 8192;
    const u16* Bk = lds + 16384 + cur * 4096;
    const u16* Bv = lds + 24576 + cur * 4096;
    bf16x8 af[4], bk8[4], bv8[4];
#pragma unroll
    for (int i = 0; i < 4; ++i) {
      int r = wm + i * 16 + fr;
      int p0 = (2 * kg) ^ (r & 7), p1 = (2 * kg + 1) ^ (r & 7);
      f32x4 a0 = *(const f32x4*)&Ab[r * 64 + p0 * 8];
      f32x4 a1 = *(const f32x4*)&Ab[r * 64 + p1 * 8];
      union { bf16x8 v; u32 w[4]; } u;
      u.w[0] = cvt_pk(a0[0], a0[1]);
      u.w[1] = cvt_pk(a0[2], a0[3]);
      u.w[2] = cvt_pk(a1[0], a1[1]);
      u.w[3] = cvt_pk(a1[2], a1[3]);
      af[i] = u.v;
    }
#pragma unroll
    for (int j = 0; j < 4; ++j) {
      int r = wn + j * 16 + fr;
      int pos = kg ^ (r & 3) ^ ((r >> 2) & 3);
      bk8[j] = *(const bf16x8*)&Bk[r * 32 + pos * 8];
      bv8[j] = *(const bf16x8*)&Bv[r * 32 + pos * 8];
    }
#pragma unroll
    for (int i = 0; i < 4; ++i)
#pragma unroll
      for (int j = 0; j < 4; ++j) {
        accK[i][j] = __builtin_amdgcn_mfma_f32_16x16x32_bf16(af[i], bk8[j], accK[i][j], 0, 0, 0);
        accV[i][j] = __builtin_amdgcn_mfma_f32_16x16x32_bf16(af[i], bv8[j], accV[i][j], 0, 0, 0);
      }

    __builtin_amdgcn_sched_barrier(0);
    __builtin_amdgcn_s_barrier();
    __builtin_amdgcn_sched_barrier(0);
  }
#undef STAGEKV

  u16* Clds = lds;  // 128*136 = 17408 u16 <= 32768
#pragma unroll
  for (int mat = 0; mat < 2; ++mat) {
    const float* bias = mat ? bV : bK;
    u16* Outp = mat ? OutV : OutK;
    __syncthreads();
#pragma unroll
    for (int i = 0; i < 4; ++i)
#pragma unroll
      for (int r = 0; r < 4; ++r) {
        int row = wm + i * 16 + kg * 4 + r;
#pragma unroll
        for (int j = 0; j < 4; ++j) {
          int ch = wn + j * 16 + fr;
          float v = mat ? accV[i][j][r] : accK[i][j][r];
          Clds[row * 136 + ch] = f2b(v + bias[nt + ch]);
        }
      }
    __syncthreads();
#pragma unroll
    for (int c = 0; c < 8; ++c) {
      int off = c * 2048 + t * 8;
      int row = off >> 7, col = off & 127;
      *(u16x8*)(Outp + (size_t)(mt + row) * 512 + nt + col) = *(const u16x8*)&Clds[row * 136 + col];
    }
  }
}

// ---------------- attention (unchanged from round 7) ----------------
__global__ __launch_bounds__(256, 2) void attn_kernel(const u16* __restrict__ Qt,
                                                      const u16* __restrict__ Kt,
                                                      const u16* __restrict__ Vt,
                                                      const float* __restrict__ biasw,
                                                      float* __restrict__ out) {
  __shared__ u16 kvlds[32768];  // K [256][64] then V [256][64]
  __shared__ float X[4096];     // partial-score exchange [64][64]
  const int t = threadIdx.x, lane = t & 63, wv = t >> 6;
  const int blk = blockIdx.x;
  const int nh = blk & 7, cg = (blk >> 3) & 7, u = (blk >> 6) & 15, b = blk >> 10;
  const int col = cg * 64 + lane;
  const int chb = nh * 64 + wv * 16;

  {
    const size_t gb = (size_t)(b * 32768 + nh * 4096 + u) * 512 + cg * 64 + (lane & 7) * 8;
#pragma unroll
    for (int ii = 0; ii < 8; ++ii) {
      int i = wv * 8 + ii;
      int r = i * 8 + (lane >> 3);          // LDS row = d*4+ks
      int d = r >> 2, ks = r & 3;
      size_t go = gb + (size_t)(d * 64 + ks * 16) * 512;
      GLDS(Kt + go, &kvlds[i * 512]);
      GLDS(Vt + go, &kvlds[16384 + i * 512]);
    }
  }

  u32x4 q0[4], q1[4];
#pragma unroll
  for (int p = 0; p < 4; ++p) {
    const u16* qp = Qt + (size_t)(b * 32768 + p * 8192 + u * 512 + col) * 512 + chb;
    q0[p] = *(const u32x4*)qp;
    q1[p] = *(const u32x4*)(qp + 8);
  }
  float br[16];
  const size_t bbase = ((size_t)(b * 8 + nh) * 16) * 8192 + u * 512 + col;
#pragma unroll
  for (int pk = 0; pk < 16; ++pk) br[pk] = biasw[bbase + (size_t)pk * 8192];

  asm volatile("s_waitcnt vmcnt(0)" ::: "memory");
  __builtin_amdgcn_sched_barrier(0);

  float sc[4][4];
#pragma unroll
  for (int p = 0; p < 4; ++p)
#pragma unroll
    for (int k = 0; k < 4; ++k) sc[p][k] = 0.f;
#pragma unroll
  for (int dd = 0; dd < 16; ++dd) {
    int rb = (wv * 16 + dd) * 4;
    float kv[4];
#pragma unroll
    for (int ks = 0; ks < 4; ++ks) kv[ks] = b2f(kvlds[(rb + ks) * 64 + lane]);
    float qd[4];
#pragma unroll
    for (int p = 0; p < 4; ++p) {
      u32 word = (dd < 8) ? q0[p][(dd >> 1) & 3] : q1[p][(dd >> 1) & 3];
      qd[p] = (dd & 1) ? b2f_hi(word) : b2f_lo(word);
    }
#pragma unroll
    for (int p = 0; p < 4; ++p)
#pragma unroll
      for (int ks = 0; ks < 4; ++ks) sc[p][ks] += qd[p] * kv[ks];
  }

#pragma unroll
  for (int pk = 0; pk < 16; ++pk) X[(wv * 16 + pk) * 64 + lane] = sc[pk >> 2][pk & 3];
  __syncthreads();

  float a[4][4];
#pragma unroll
  for (int p = 0; p < 4; ++p) {
    float s[4];
#pragma unroll
    for (int ks = 0; ks < 4; ++ks) {
      int pk = p * 4 + ks;
      float tot = X[pk * 64 + lane] + X[(16 + pk) * 64 + lane] + X[(32 + pk) * 64 + lane] +
                  X[(48 + pk) * 64 + lane];
      s[ks] = tot * 0.125f + br[pk];
    }
    float mx = fmaxf(fmaxf(s[0], s[1]), fmaxf(s[2], s[3]));
    float e0 = __expf(s[0] - mx), e1 = __expf(s[1] - mx), e2 = __expf(s[2] - mx),
          e3 = __expf(s[3] - mx);
    float inv = 1.f / (e0 + e1 + e2 + e3);
    a[p][0] = e0 * inv; a[p][1] = e1 * inv; a[p][2] = e2 * inv; a[p][3] = e3 * inv;
  }

  float o[4][16];
#pragma unroll
  for (int dd = 0; dd < 16; ++dd) {
    int rb = (wv * 16 + dd) * 4;
    float vv[4];
#pragma unroll
    for (int ks = 0; ks < 4; ++ks) vv[ks] = b2f(kvlds[16384 + (rb + ks) * 64 + lane]);
#pragma unroll
    for (int p = 0; p < 4; ++p)
      o[p][dd] = a[p][0] * vv[0] + a[p][1] * vv[1] + a[p][2] * vv[2] + a[p][3] * vv[3];
  }
#pragma unroll
  for (int p = 0; p < 4; ++p) {
    float* op = out + (size_t)(b * 32768 + p * 8192 + u * 512 + col) * 512 + chb;
#pragma unroll
    for (int c4 = 0; c4 < 4; ++c4) {
      float4 vv = {o[p][c4 * 4 + 0], o[p][c4 * 4 + 1], o[p][c4 * 4 + 2], o[p][c4 * 4 + 3]};
      *(float4*)(op + c4 * 4) = vv;
    }
  }
}

// ---------------- launch ----------------
extern "C" void kernel_launch(void* const* d_in, const int* in_sizes, int n_in,
                              void* d_out, int out_size, void* d_ws, size_t ws_size,
                              hipStream_t stream) {
  (void)in_sizes; (void)n_in; (void)out_size; (void)ws_size;
  const float* s     = (const float*)d_in[0];
  const float* x     = (const float*)d_in[1];
  const float* s_pos = (const float*)d_in[2];
  const float* x_pos = (const float*)d_in[3];
  const float* Wq = (const float*)d_in[4];  const float* bq = (const float*)d_in[5];
  const float* Wk = (const float*)d_in[6];  const float* bk = (const float*)d_in[7];
  const float* Wv = (const float*)d_in[8];  const float* bv = (const float*)d_in[9];
  const float* pw1 = (const float*)d_in[10]; const float* pb1 = (const float*)d_in[11];
  const float* bng = (const float*)d_in[12]; const float* bnb = (const float*)d_in[13];
  const float* bnm = (const float*)d_in[14]; const float* bnv = (const float*)d_in[15];
  const float* pw2 = (const float*)d_in[16]; const float* pb2 = (const float*)d_in[17];
  float* out = (float*)d_out;

  char* ws = (char*)d_ws;
  u16* Qt = (u16*)ws;                        // 67,108,864 B
  u16* Kt = (u16*)(ws + 67108864);           // 67,108,864 B
  u16* Vt = (u16*)(ws + 134217728);          // 67,108,864 B
  float* biasw = (float*)(ws + 201326592);   //  8,388,608 B
  u16* Wt = (u16*)(ws + 209715200);          //  1,572,864 B

  wt_kernel<<<dim3(1024, 3), 256, 0, stream>>>(Wq, Wk, Wv, Wt);
  bias_kernel<<<dim3(256), 256, 0, stream>>>(x_pos, s_pos, pw1, pb1, bng, bnb, bnm, bnv,
                                             pw2, pb2, biasw);
  gemm_kernel<<<dim3(2048), 256, 0, stream>>>(x, Wt, bq, Qt);
  gemmkv_kernel<<<dim3(2048), 256, 0, stream>>>(s, Wt + 262144, Wt + 524288, bk, bv, Kt, Vt);
  attn_kernel<<<dim3(2048), 256, 0, stream>>>(Qt, Kt, Vt, biasw, out);
}